// Round 13
// baseline (195.793 us; speedup 1.0000x reference)
//
#include <hip/hip_runtime.h>

typedef unsigned int u32;
typedef unsigned long long u64;
typedef float f32x4 __attribute__((ext_vector_type(4)));

#define T_ 4
#define B_ 32
#define E_ 1024
#define H_ 16
#define HD_ 64
#define CACHE_ 4096
#define S_ 4100
#define SPLIT_ 2
#define NEGINF (-__builtin_inff())

// ---------------- prep: blocks 0..31 = mask compaction; 32..415 = QKV proj ----------------
// Proj: 32x32 output tiles, BK=64, 2x2 register tile per thread (0.5 LDS reads/FMA).
__global__ __launch_bounds__(256) void prep_kernel(
    const float* __restrict__ query,
    const float* __restrict__ Wq, const float* __restrict__ bq,
    const float* __restrict__ Wk, const float* __restrict__ bk,
    const float* __restrict__ Wv, const float* __restrict__ bv,
    const unsigned char* __restrict__ mask8,
    float* __restrict__ qs, float* __restrict__ kn, float* __restrict__ vn,
    int* __restrict__ cidx, int* __restrict__ ccnt, int* __restrict__ flag)
{
    const int tid = threadIdx.x;
    if (blockIdx.x < 32) {
        // ---------- compaction: 2 barriers total ----------
        const int b = blockIdx.x;
        const int w = tid >> 6, l = tid & 63;
        const int* mask32 = (const int*)mask8;
        __shared__ int cnt_s;
        __shared__ int rcnt[64];      // [round*4 + wave]
        __shared__ int roff[64];
        __shared__ int total_s;

        int cnt = 0;
        for (int i = tid; i < 8192; i += 256) cnt += (mask8[i] != 0) ? 1 : 0;
#pragma unroll
        for (int off = 32; off; off >>= 1) cnt += __shfl_xor(cnt, off);
        if (tid == 0) cnt_s = 0;
        __syncthreads();
        if (l == 0) atomicAdd(&cnt_s, cnt);
        __syncthreads();
        const int mode = (cnt_s > 2048) ? 1 : 0;
        if (b == 0 && tid == 0) *flag = mode;

        u32 okbits = 0;
        const size_t mbase = (size_t)b * S_;
#pragma unroll
        for (int r = 0; r < 16; r++) {
            int s = r * 256 + tid;
            bool ok = mode ? (mask8[mbase + s] == 0) : (mask32[mbase + s] == 0);
            okbits |= (ok ? 1u : 0u) << r;
            u64 bal = __ballot(ok);
            if (l == 0) rcnt[r * 4 + w] = (int)__popcll(bal);
        }
        __syncthreads();
        if (tid < 64) {
            int c = rcnt[tid];
            int incl = c;
#pragma unroll
            for (int d = 1; d < 64; d <<= 1) {
                int v = __shfl_up(incl, d);
                if (l >= d) incl += v;
            }
            roff[tid] = incl - c;
            if (tid == 63) total_s = incl;
        }
        __syncthreads();
#pragma unroll
        for (int r = 0; r < 16; r++) {
            bool ok = (okbits >> r) & 1;
            u64 bal = __ballot(ok);
            int pre = (int)__popcll(bal & ((1ull << l) - 1));
            if (ok) cidx[b * CACHE_ + roff[r * 4 + w] + pre] = r * 256 + tid;
        }
        if (tid == 0) ccnt[b] = total_s;
        return;
    }

    // ---------- QKV projection: 32x32 tiles, BK=64, 2x2 reg tile ----------
    const int bx = blockIdx.x - 32;       // 0..383
    const int mat = bx >> 7;              // 0..2 (128 blocks each)
    const int rem = bx & 127;             // 4 rt x 32 ct
    const int rt = rem >> 5, ct = rem & 31;
    const int r0 = rt * 32, c0 = ct * 32;
    const float* W    = (mat == 0) ? Wq : (mat == 1) ? Wk : Wv;
    const float* bias = (mat == 0) ? bq : (mat == 1) ? bk : bv;

    __shared__ float A_l[32][65];
    __shared__ float W_l[32][65];
    const int tr = tid >> 4, tc = tid & 15;
    float a00 = 0.f, a01 = 0.f, a10 = 0.f, a11 = 0.f;

    for (int k0 = 0; k0 < 1024; k0 += 64) {
        __syncthreads();
#pragma unroll
        for (int jj = 0; jj < 2; jj++) {
            int j = tid * 2 + jj;
            int rr = j >> 4, kk = (j & 15) * 4;
            float4 va = *(const float4*)(query + (size_t)(r0 + rr) * 1024 + k0 + kk);
            A_l[rr][kk] = va.x; A_l[rr][kk + 1] = va.y;
            A_l[rr][kk + 2] = va.z; A_l[rr][kk + 3] = va.w;
            float4 vw = *(const float4*)(W + (size_t)(c0 + rr) * 1024 + k0 + kk);
            W_l[rr][kk] = vw.x; W_l[rr][kk + 1] = vw.y;
            W_l[rr][kk + 2] = vw.z; W_l[rr][kk + 3] = vw.w;
        }
        __syncthreads();
#pragma unroll
        for (int kk = 0; kk < 64; kk++) {
            float x0 = A_l[tr * 2][kk], x1 = A_l[tr * 2 + 1][kk];
            float y0 = W_l[tc * 2][kk], y1 = W_l[tc * 2 + 1][kk];
            a00 += x0 * y0; a01 += x0 * y1;
            a10 += x1 * y0; a11 += x1 * y1;
        }
    }
    float accs[2][2] = {{a00, a01}, {a10, a11}};
#pragma unroll
    for (int i = 0; i < 2; i++) {
#pragma unroll
        for (int j = 0; j < 2; j++) {
            int row = r0 + tr * 2 + i, col = c0 + tc * 2 + j;
            int t = row >> 5, b = row & 31;
            int h = col >> 6, d = col & 63;
            float val = accs[i][j] + bias[col];
            size_t oidx = ((size_t)((b * H_ + h) * T_ + t)) * HD_ + d;
            if (mat == 0) qs[oidx] = val * 0.125f;
            else if (mat == 1) kn[oidx] = val;
            else vn[oidx] = val;
        }
    }
}

// ---------------- attention: 128B-transaction, lane-local-softmax flash decode ----------------
// (round-11 kernel: measured best — compacted gather, nt loads, reg A/B dbuf)
__global__ __launch_bounds__(256, 4) void attn_kernel(
    const float* __restrict__ kcache, const float* __restrict__ vcache,
    const float* __restrict__ qs,
    const int* __restrict__ cidx, const int* __restrict__ ccnt,
    float* __restrict__ part_ml, float* __restrict__ part_acc)
{
    const int bid = blockIdx.x;
    const int bh = bid >> 1, split = bid & 1;
    const int b = bh >> 4;
    const int tid = threadIdx.x;
    const int w = tid >> 6, l = tid & 63;
    const int sub = l & 7, r8 = l >> 3;

    __shared__ float q_l[256];
    __shared__ int cidx_l[2048];

    const int cnt = ccnt[b];
    const int half = (cnt + 1) >> 1;
    const int lo = split * half;
    const int hi = min(cnt, lo + half);
    const int n = hi - lo;

    q_l[tid] = qs[bh * 256 + tid];
    for (int i = tid; i < n; i += 256) cidx_l[i] = cidx[b * CACHE_ + lo + i];
    __syncthreads();

    float4 qa[4], qb[4];
#pragma unroll
    for (int t = 0; t < 4; t++) {
        qa[t] = *(const float4*)&q_l[t * 64 + sub * 4];
        qb[t] = *(const float4*)&q_l[t * 64 + 32 + sub * 4];
    }

    float4 o0[4], o1[4];
#pragma unroll
    for (int t = 0; t < 4; t++) {
        o0[t] = make_float4(0.f, 0.f, 0.f, 0.f);
        o1[t] = make_float4(0.f, 0.f, 0.f, 0.f);
    }
    float m[4] = {NEGINF, NEGINF, NEGINF, NEGINF};
    float L[4] = {0.f, 0.f, 0.f, 0.f};

    const float* kb = kcache + (size_t)bh * (CACHE_ * HD_) + sub * 4;
    const float* vb = vcache + (size_t)bh * (CACHE_ * HD_) + sub * 4;

    const int nch = (n + 31) >> 5;        // 32 rows per block-chunk (8 per wave)
    const int pbase = w * 8 + r8;

    f32x4 kA0, kA1, vA0, vA1, kB0, kB1, vB0, vB1;

#define ISSUE(K0, K1, V0, V1, CC) {                                       \
        int idx_ = cidx_l[min(pbase + (CC) * 32, n - 1)];                  \
        const f32x4* kp_ = (const f32x4*)(kb + ((size_t)idx_ << 6));       \
        const f32x4* vp_ = (const f32x4*)(vb + ((size_t)idx_ << 6));       \
        K0 = __builtin_nontemporal_load(kp_);                              \
        K1 = __builtin_nontemporal_load(kp_ + 8);                          \
        V0 = __builtin_nontemporal_load(vp_);                              \
        V1 = __builtin_nontemporal_load(vp_ + 8);                          \
    }

#define PROCESS(K0, K1, V0, V1, CC) {                                               \
        const bool valid_ = ((CC) * 32 + pbase) < n;                                \
        _Pragma("unroll")                                                           \
        for (int t = 0; t < 4; t++) {                                               \
            float part = qa[t].x * K0.x + qa[t].y * K0.y + qa[t].z * K0.z           \
                       + qa[t].w * K0.w + qb[t].x * K1.x + qb[t].y * K1.y           \
                       + qb[t].z * K1.z + qb[t].w * K1.w;                           \
            part += __shfl_xor(part, 1);                                            \
            part += __shfl_xor(part, 2);                                            \
            part += __shfl_xor(part, 4);                                            \
            float s = valid_ ? part : NEGINF;                                       \
            if (s > m[t] + 8.f) {       /* defer-max: rare rescale */               \
                float fac = __expf(m[t] - s);                                       \
                L[t] *= fac;                                                        \
                o0[t].x *= fac; o0[t].y *= fac; o0[t].z *= fac; o0[t].w *= fac;     \
                o1[t].x *= fac; o1[t].y *= fac; o1[t].z *= fac; o1[t].w *= fac;     \
                m[t] = s;                                                           \
            }                                                                       \
            float e = (s == NEGINF) ? 0.f : __expf(s - m[t]);                       \
            L[t] += e;                                                              \
            o0[t].x += e * V0.x; o0[t].y += e * V0.y;                               \
            o0[t].z += e * V0.z; o0[t].w += e * V0.w;                               \
            o1[t].x += e * V1.x; o1[t].y += e * V1.y;                               \
            o1[t].z += e * V1.z; o1[t].w += e * V1.w;                               \
        }                                                                           \
    }

    if (nch > 0) ISSUE(kA0, kA1, vA0, vA1, 0);
    if (nch > 1) ISSUE(kB0, kB1, vB0, vB1, 1);

    for (int c = 0; c < nch; c += 2) {
        PROCESS(kA0, kA1, vA0, vA1, c);
        if (c + 2 < nch) ISSUE(kA0, kA1, vA0, vA1, c + 2);
        if (c + 1 < nch) {
            PROCESS(kB0, kB1, vB0, vB1, c + 1);
            if (c + 3 < nch) ISSUE(kB0, kB1, vB0, vB1, c + 3);
        }
    }
#undef ISSUE
#undef PROCESS

    // ---- end merge across the 8 r8-groups (lanes differ in bits 3,4,5) ----
    const int pidx = bid * 4 + w;           // [0, 4096)
#pragma unroll
    for (int t = 0; t < 4; t++) {
        float M = m[t];
        M = fmaxf(M, __shfl_xor(M, 8));
        M = fmaxf(M, __shfl_xor(M, 16));
        M = fmaxf(M, __shfl_xor(M, 32));
        float fac = (m[t] == NEGINF) ? 0.f : __expf(m[t] - M);
        float Lr = L[t] * fac;
        Lr += __shfl_xor(Lr, 8);
        Lr += __shfl_xor(Lr, 16);
        Lr += __shfl_xor(Lr, 32);
        float a0x = o0[t].x * fac, a0y = o0[t].y * fac,
              a0z = o0[t].z * fac, a0w = o0[t].w * fac;
        float a1x = o1[t].x * fac, a1y = o1[t].y * fac,
              a1z = o1[t].z * fac, a1w = o1[t].w * fac;
#pragma unroll
        for (int off = 8; off <= 32; off <<= 1) {
            a0x += __shfl_xor(a0x, off); a0y += __shfl_xor(a0y, off);
            a0z += __shfl_xor(a0z, off); a0w += __shfl_xor(a0w, off);
            a1x += __shfl_xor(a1x, off); a1y += __shfl_xor(a1y, off);
            a1z += __shfl_xor(a1z, off); a1w += __shfl_xor(a1w, off);
        }
        if (r8 == 0) {
            *(float4*)&part_acc[((size_t)pidx * 4 + t) * HD_ + sub * 4] =
                make_float4(a0x, a0y, a0z, a0w);
            *(float4*)&part_acc[((size_t)pidx * 4 + t) * HD_ + 32 + sub * 4] =
                make_float4(a1x, a1y, a1z, a1w);
        }
        if (l == 0) {
            part_ml[pidx * 8 + t * 2 + 0] = M;
            part_ml[pidx * 8 + t * 2 + 1] = Lr;
        }
    }
}

// ---------------- merge partials + new tokens + normalize ----------------
__global__ __launch_bounds__(256) void merge_kernel(
    const float* __restrict__ part_ml, const float* __restrict__ part_acc,
    const float* __restrict__ qs, const float* __restrict__ kn,
    const float* __restrict__ vn,
    const unsigned char* __restrict__ mask8, const int* __restrict__ flag,
    float* __restrict__ attn_out)
{
    const int bh = blockIdx.x;
    const int b = bh >> 4, h = bh & 15;
    const int tid = threadIdx.x;
    const int t = tid >> 6, d = tid & 63;
    const int mode = *flag;
    const int* mask32 = (const int*)mask8;

    float M = NEGINF;
#pragma unroll
    for (int i = 0; i < 8; i++) M = fmaxf(M, part_ml[(bh * 8 + i) * 8 + t * 2]);
    float acc = 0.f, L = 0.f;
#pragma unroll
    for (int i = 0; i < 8; i++) {
        float mi = part_ml[(bh * 8 + i) * 8 + t * 2];
        float li = part_ml[(bh * 8 + i) * 8 + t * 2 + 1];
        if (mi > NEGINF) {
            float wgt = __expf(mi - M);
            L += li * wgt;
            acc += part_acc[((size_t)(bh * 8 + i) * 4 + t) * HD_ + d] * wgt;
        }
    }

    float qv = qs[bh * 256 + t * 64 + d];
    float sn[4];
#pragma unroll
    for (int i = 0; i < 4; i++) {
        size_t mi_ = (size_t)b * S_ + CACHE_ + i;
        bool masked = mode ? (mask8[mi_] != 0) : (mask32[mi_] != 0);
        float prod = qv * kn[bh * 256 + i * 64 + d];
        prod += __shfl_xor(prod, 1);
        prod += __shfl_xor(prod, 2);
        prod += __shfl_xor(prod, 4);
        prod += __shfl_xor(prod, 8);
        prod += __shfl_xor(prod, 16);
        prod += __shfl_xor(prod, 32);
        sn[i] = masked ? NEGINF : prod;
    }
    float M2 = M;
#pragma unroll
    for (int i = 0; i < 4; i++) M2 = fmaxf(M2, sn[i]);
    if (M2 > NEGINF) {
        if (M > NEGINF) {
            float wo = __expf(M - M2);
            acc *= wo; L *= wo;
        }
#pragma unroll
        for (int i = 0; i < 4; i++) {
            if (sn[i] > NEGINF) {
                float e = __expf(sn[i] - M2);
                L += e;
                acc += e * vn[bh * 256 + i * 64 + d];
            }
        }
    }
    float o = (L > 0.f) ? acc / L : 0.f;
    attn_out[(size_t)(t * B_ + b) * E_ + h * HD_ + d] = o;
}

// ---------------- output projection: 32x32 tiles, BK=64, 2x2 reg tile (128 blocks) ----------------
__global__ __launch_bounds__(256) void oproj_kernel(
    const float* __restrict__ A,
    const float* __restrict__ W, const float* __restrict__ bias,
    float* __restrict__ out)
{
    const int bx = blockIdx.x;            // 128 blocks: 4 rt x 32 ct
    const int rt = bx >> 5, ct = bx & 31;
    const int r0 = rt * 32, c0 = ct * 32;
    const int tid = threadIdx.x;

    __shared__ float A_l[32][65];
    __shared__ float W_l[32][65];
    const int tr = tid >> 4, tc = tid & 15;
    float a00 = 0.f, a01 = 0.f, a10 = 0.f, a11 = 0.f;

    for (int k0 = 0; k0 < 1024; k0 += 64) {
        __syncthreads();
#pragma unroll
        for (int jj = 0; jj < 2; jj++) {
            int j = tid * 2 + jj;
            int rr = j >> 4, kk = (j & 15) * 4;
            float4 va = *(const float4*)(A + (size_t)(r0 + rr) * 1024 + k0 + kk);
            A_l[rr][kk] = va.x; A_l[rr][kk + 1] = va.y;
            A_l[rr][kk + 2] = va.z; A_l[rr][kk + 3] = va.w;
            float4 vw = *(const float4*)(W + (size_t)(c0 + rr) * 1024 + k0 + kk);
            W_l[rr][kk] = vw.x; W_l[rr][kk + 1] = vw.y;
            W_l[rr][kk + 2] = vw.z; W_l[rr][kk + 3] = vw.w;
        }
        __syncthreads();
#pragma unroll
        for (int kk = 0; kk < 64; kk++) {
            float x0 = A_l[tr * 2][kk], x1 = A_l[tr * 2 + 1][kk];
            float y0 = W_l[tc * 2][kk], y1 = W_l[tc * 2 + 1][kk];
            a00 += x0 * y0; a01 += x0 * y1;
            a10 += x1 * y0; a11 += x1 * y1;
        }
    }
    const int row0 = r0 + tr * 2, col0 = c0 + tc * 2;
    out[(size_t)row0 * 1024 + col0]           = a00 + bias[col0];
    out[(size_t)row0 * 1024 + col0 + 1]       = a01 + bias[col0 + 1];
    out[(size_t)(row0 + 1) * 1024 + col0]     = a10 + bias[col0];
    out[(size_t)(row0 + 1) * 1024 + col0 + 1] = a11 + bias[col0 + 1];
}

extern "C" void kernel_launch(void* const* d_in, const int* in_sizes, int n_in,
                              void* d_out, int out_size, void* d_ws, size_t ws_size,
                              hipStream_t stream) {
    const float* query = (const float*)d_in[0];
    // d_in[1] = key: unused by the reference (k_new/v_new project from query)
    const unsigned char* mask = (const unsigned char*)d_in[2];
    const float* kcache = (const float*)d_in[3];
    const float* vcache = (const float*)d_in[4];
    const float* Wq = (const float*)d_in[5];
    const float* bq = (const float*)d_in[6];
    const float* Wk = (const float*)d_in[7];
    const float* bk = (const float*)d_in[8];
    const float* Wv = (const float*)d_in[9];
    const float* bv = (const float*)d_in[10];
    const float* Wo = (const float*)d_in[11];
    const float* bo = (const float*)d_in[12];

    char* ws = (char*)d_ws;
    float* qs   = (float*)(ws);                       // 512 KB
    float* kn   = (float*)(ws + ( 512ull << 10));     // 512 KB
    float* vn   = (float*)(ws + (1024ull << 10));     // 512 KB
    float* att  = (float*)(ws + (1536ull << 10));     // 512 KB
    int*   flag = (int*)  (ws + (2048ull << 10));     // 4 B
    int*   cidx = (int*)  (ws + (2049ull << 10));     // 512 KB
    int*   ccnt = (int*)  (ws + (2562ull << 10));     // 128 B
    float* pml  = (float*)(ws + (2563ull << 10));     // 128 KB
    float* pacc = (float*)(ws + (3072ull << 10));     // 4 MB

    prep_kernel<<<32 + 384, 256, 0, stream>>>(query, Wq, bq, Wk, bk, Wv, bv,
                                              mask, qs, kn, vn, cidx, ccnt, flag);
    attn_kernel<<<512 * SPLIT_, 256, 0, stream>>>(kcache, vcache, qs, cidx, ccnt, pml, pacc);
    merge_kernel<<<512, 256, 0, stream>>>(pml, pacc, qs, kn, vn, mask, flag, att);
    oproj_kernel<<<128, 256, 0, stream>>>(att, Wo, bo, (float*)d_out);
}

// Round 14
// 158.365 us; speedup vs baseline: 1.2363x; 1.2363x over previous
//
#include <hip/hip_runtime.h>

typedef unsigned int u32;
typedef unsigned long long u64;
typedef float f32x4 __attribute__((ext_vector_type(4)));

#define T_ 4
#define B_ 32
#define E_ 1024
#define H_ 16
#define HD_ 64
#define CACHE_ 4096
#define S_ 4100
#define SPLIT_ 2
#define NEGINF (-__builtin_inff())

// ---------------- prep: blocks 0..31 = mask compaction; 32..1567 = QKV proj ----------------
// Proj: 16x16 output tiles (512 blocks/matrix, 6.1 blocks/CU), BK=64,
// LDS read as float4 (ds_read_b128): 32 LDS insts + 64 FMA per k-step.
__global__ __launch_bounds__(256) void prep_kernel(
    const float* __restrict__ query,
    const float* __restrict__ Wq, const float* __restrict__ bq,
    const float* __restrict__ Wk, const float* __restrict__ bk,
    const float* __restrict__ Wv, const float* __restrict__ bv,
    const unsigned char* __restrict__ mask8,
    float* __restrict__ qs, float* __restrict__ kn, float* __restrict__ vn,
    int* __restrict__ cidx, int* __restrict__ ccnt, int* __restrict__ flag)
{
    const int tid = threadIdx.x;
    if (blockIdx.x < 32) {
        // ---------- compaction: 2 barriers total ----------
        const int b = blockIdx.x;
        const int w = tid >> 6, l = tid & 63;
        const int* mask32 = (const int*)mask8;
        __shared__ int cnt_s;
        __shared__ int rcnt[64];      // [round*4 + wave]
        __shared__ int roff[64];
        __shared__ int total_s;

        int cnt = 0;
        for (int i = tid; i < 8192; i += 256) cnt += (mask8[i] != 0) ? 1 : 0;
#pragma unroll
        for (int off = 32; off; off >>= 1) cnt += __shfl_xor(cnt, off);
        if (tid == 0) cnt_s = 0;
        __syncthreads();
        if (l == 0) atomicAdd(&cnt_s, cnt);
        __syncthreads();
        const int mode = (cnt_s > 2048) ? 1 : 0;
        if (b == 0 && tid == 0) *flag = mode;

        u32 okbits = 0;
        const size_t mbase = (size_t)b * S_;
#pragma unroll
        for (int r = 0; r < 16; r++) {
            int s = r * 256 + tid;
            bool ok = mode ? (mask8[mbase + s] == 0) : (mask32[mbase + s] == 0);
            okbits |= (ok ? 1u : 0u) << r;
            u64 bal = __ballot(ok);
            if (l == 0) rcnt[r * 4 + w] = (int)__popcll(bal);
        }
        __syncthreads();
        if (tid < 64) {
            int c = rcnt[tid];
            int incl = c;
#pragma unroll
            for (int d = 1; d < 64; d <<= 1) {
                int v = __shfl_up(incl, d);
                if (l >= d) incl += v;
            }
            roff[tid] = incl - c;
            if (tid == 63) total_s = incl;
        }
        __syncthreads();
#pragma unroll
        for (int r = 0; r < 16; r++) {
            bool ok = (okbits >> r) & 1;
            u64 bal = __ballot(ok);
            int pre = (int)__popcll(bal & ((1ull << l) - 1));
            if (ok) cidx[b * CACHE_ + roff[r * 4 + w] + pre] = r * 256 + tid;
        }
        if (tid == 0) ccnt[b] = total_s;
        return;
    }

    // ---------- QKV projection, 16x16 tiles, BK=64, float4 LDS reads ----------
    const int bx = blockIdx.x - 32;       // 0..1535
    const int mat = bx >> 9;              // 0..2 (512 blocks each)
    const int rem = bx & 511;
    const int rt = rem >> 6, ct = rem & 63;
    const int r0 = rt * 16, c0 = ct * 16;
    const float* W    = (mat == 0) ? Wq : (mat == 1) ? Wk : Wv;
    const float* bias = (mat == 0) ? bq : (mat == 1) ? bk : bv;

    __shared__ float A_l[16][68];         // stride 68: rows 16B-aligned for b128
    __shared__ float W_l[16][68];
    const int r = tid >> 4, cc = tid & 15;
    float acc = 0.f;

    for (int k0 = 0; k0 < 1024; k0 += 64) {
        __syncthreads();
        if (tid < 128) {
            int j0 = tid * 2;
#pragma unroll
            for (int jj = 0; jj < 2; jj++) {
                int j = j0 + jj;
                int ar = j >> 4, kk = (j & 15) * 4;
                float4 v = *(const float4*)(query + (size_t)(r0 + ar) * 1024 + k0 + kk);
                *(float4*)&A_l[ar][kk] = v;
            }
        } else {
            int j0 = (tid - 128) * 2;
#pragma unroll
            for (int jj = 0; jj < 2; jj++) {
                int j = j0 + jj;
                int wr = j >> 4, kk = (j & 15) * 4;
                float4 v = *(const float4*)(W + (size_t)(c0 + wr) * 1024 + k0 + kk);
                *(float4*)&W_l[wr][kk] = v;
            }
        }
        __syncthreads();
#pragma unroll
        for (int kk = 0; kk < 64; kk += 4) {
            float4 a4 = *(const float4*)&A_l[r][kk];
            float4 w4 = *(const float4*)&W_l[cc][kk];
            acc += a4.x * w4.x + a4.y * w4.y + a4.z * w4.z + a4.w * w4.w;
        }
    }
    const int row = r0 + r, col = c0 + cc;
    const int t = row >> 5, b = row & 31;
    const int h = col >> 6, d = col & 63;
    float val = acc + bias[col];
    size_t oidx = ((size_t)((b * H_ + h) * T_ + t)) * HD_ + d;
    if (mat == 0) qs[oidx] = val * 0.125f;
    else if (mat == 1) kn[oidx] = val;
    else vn[oidx] = val;
}

// ---------------- attention: 128B-transaction, lane-local-softmax flash decode ----------------
// (round-11 kernel: measured best — compacted gather, nt loads, reg A/B dbuf)
__global__ __launch_bounds__(256, 4) void attn_kernel(
    const float* __restrict__ kcache, const float* __restrict__ vcache,
    const float* __restrict__ qs,
    const int* __restrict__ cidx, const int* __restrict__ ccnt,
    float* __restrict__ part_ml, float* __restrict__ part_acc)
{
    const int bid = blockIdx.x;
    const int bh = bid >> 1, split = bid & 1;
    const int b = bh >> 4;
    const int tid = threadIdx.x;
    const int w = tid >> 6, l = tid & 63;
    const int sub = l & 7, r8 = l >> 3;

    __shared__ float q_l[256];
    __shared__ int cidx_l[2048];

    const int cnt = ccnt[b];
    const int half = (cnt + 1) >> 1;
    const int lo = split * half;
    const int hi = min(cnt, lo + half);
    const int n = hi - lo;

    q_l[tid] = qs[bh * 256 + tid];
    for (int i = tid; i < n; i += 256) cidx_l[i] = cidx[b * CACHE_ + lo + i];
    __syncthreads();

    float4 qa[4], qb[4];
#pragma unroll
    for (int t = 0; t < 4; t++) {
        qa[t] = *(const float4*)&q_l[t * 64 + sub * 4];
        qb[t] = *(const float4*)&q_l[t * 64 + 32 + sub * 4];
    }

    float4 o0[4], o1[4];
#pragma unroll
    for (int t = 0; t < 4; t++) {
        o0[t] = make_float4(0.f, 0.f, 0.f, 0.f);
        o1[t] = make_float4(0.f, 0.f, 0.f, 0.f);
    }
    float m[4] = {NEGINF, NEGINF, NEGINF, NEGINF};
    float L[4] = {0.f, 0.f, 0.f, 0.f};

    const float* kb = kcache + (size_t)bh * (CACHE_ * HD_) + sub * 4;
    const float* vb = vcache + (size_t)bh * (CACHE_ * HD_) + sub * 4;

    const int nch = (n + 31) >> 5;        // 32 rows per block-chunk (8 per wave)
    const int pbase = w * 8 + r8;

    f32x4 kA0, kA1, vA0, vA1, kB0, kB1, vB0, vB1;

#define ISSUE(K0, K1, V0, V1, CC) {                                       \
        int idx_ = cidx_l[min(pbase + (CC) * 32, n - 1)];                  \
        const f32x4* kp_ = (const f32x4*)(kb + ((size_t)idx_ << 6));       \
        const f32x4* vp_ = (const f32x4*)(vb + ((size_t)idx_ << 6));       \
        K0 = __builtin_nontemporal_load(kp_);                              \
        K1 = __builtin_nontemporal_load(kp_ + 8);                          \
        V0 = __builtin_nontemporal_load(vp_);                              \
        V1 = __builtin_nontemporal_load(vp_ + 8);                          \
    }

#define PROCESS(K0, K1, V0, V1, CC) {                                               \
        const bool valid_ = ((CC) * 32 + pbase) < n;                                \
        _Pragma("unroll")                                                           \
        for (int t = 0; t < 4; t++) {                                               \
            float part = qa[t].x * K0.x + qa[t].y * K0.y + qa[t].z * K0.z           \
                       + qa[t].w * K0.w + qb[t].x * K1.x + qb[t].y * K1.y           \
                       + qb[t].z * K1.z + qb[t].w * K1.w;                           \
            part += __shfl_xor(part, 1);                                            \
            part += __shfl_xor(part, 2);                                            \
            part += __shfl_xor(part, 4);                                            \
            float s = valid_ ? part : NEGINF;                                       \
            if (s > m[t] + 8.f) {       /* defer-max: rare rescale */               \
                float fac = __expf(m[t] - s);                                       \
                L[t] *= fac;                                                        \
                o0[t].x *= fac; o0[t].y *= fac; o0[t].z *= fac; o0[t].w *= fac;     \
                o1[t].x *= fac; o1[t].y *= fac; o1[t].z *= fac; o1[t].w *= fac;     \
                m[t] = s;                                                           \
            }                                                                       \
            float e = (s == NEGINF) ? 0.f : __expf(s - m[t]);                       \
            L[t] += e;                                                              \
            o0[t].x += e * V0.x; o0[t].y += e * V0.y;                               \
            o0[t].z += e * V0.z; o0[t].w += e * V0.w;                               \
            o1[t].x += e * V1.x; o1[t].y += e * V1.y;                               \
            o1[t].z += e * V1.z; o1[t].w += e * V1.w;                               \
        }                                                                           \
    }

    if (nch > 0) ISSUE(kA0, kA1, vA0, vA1, 0);
    if (nch > 1) ISSUE(kB0, kB1, vB0, vB1, 1);

    for (int c = 0; c < nch; c += 2) {
        PROCESS(kA0, kA1, vA0, vA1, c);
        if (c + 2 < nch) ISSUE(kA0, kA1, vA0, vA1, c + 2);
        if (c + 1 < nch) {
            PROCESS(kB0, kB1, vB0, vB1, c + 1);
            if (c + 3 < nch) ISSUE(kB0, kB1, vB0, vB1, c + 3);
        }
    }
#undef ISSUE
#undef PROCESS

    // ---- end merge across the 8 r8-groups (lanes differ in bits 3,4,5) ----
    const int pidx = bid * 4 + w;           // [0, 4096)
#pragma unroll
    for (int t = 0; t < 4; t++) {
        float M = m[t];
        M = fmaxf(M, __shfl_xor(M, 8));
        M = fmaxf(M, __shfl_xor(M, 16));
        M = fmaxf(M, __shfl_xor(M, 32));
        float fac = (m[t] == NEGINF) ? 0.f : __expf(m[t] - M);
        float Lr = L[t] * fac;
        Lr += __shfl_xor(Lr, 8);
        Lr += __shfl_xor(Lr, 16);
        Lr += __shfl_xor(Lr, 32);
        float a0x = o0[t].x * fac, a0y = o0[t].y * fac,
              a0z = o0[t].z * fac, a0w = o0[t].w * fac;
        float a1x = o1[t].x * fac, a1y = o1[t].y * fac,
              a1z = o1[t].z * fac, a1w = o1[t].w * fac;
#pragma unroll
        for (int off = 8; off <= 32; off <<= 1) {
            a0x += __shfl_xor(a0x, off); a0y += __shfl_xor(a0y, off);
            a0z += __shfl_xor(a0z, off); a0w += __shfl_xor(a0w, off);
            a1x += __shfl_xor(a1x, off); a1y += __shfl_xor(a1y, off);
            a1z += __shfl_xor(a1z, off); a1w += __shfl_xor(a1w, off);
        }
        if (r8 == 0) {
            *(float4*)&part_acc[((size_t)pidx * 4 + t) * HD_ + sub * 4] =
                make_float4(a0x, a0y, a0z, a0w);
            *(float4*)&part_acc[((size_t)pidx * 4 + t) * HD_ + 32 + sub * 4] =
                make_float4(a1x, a1y, a1z, a1w);
        }
        if (l == 0) {
            part_ml[pidx * 8 + t * 2 + 0] = M;
            part_ml[pidx * 8 + t * 2 + 1] = Lr;
        }
    }
}

// ---------------- merge partials + new tokens + normalize ----------------
__global__ __launch_bounds__(256) void merge_kernel(
    const float* __restrict__ part_ml, const float* __restrict__ part_acc,
    const float* __restrict__ qs, const float* __restrict__ kn,
    const float* __restrict__ vn,
    const unsigned char* __restrict__ mask8, const int* __restrict__ flag,
    float* __restrict__ attn_out)
{
    const int bh = blockIdx.x;
    const int b = bh >> 4, h = bh & 15;
    const int tid = threadIdx.x;
    const int t = tid >> 6, d = tid & 63;
    const int mode = *flag;
    const int* mask32 = (const int*)mask8;

    float M = NEGINF;
#pragma unroll
    for (int i = 0; i < 8; i++) M = fmaxf(M, part_ml[(bh * 8 + i) * 8 + t * 2]);
    float acc = 0.f, L = 0.f;
#pragma unroll
    for (int i = 0; i < 8; i++) {
        float mi = part_ml[(bh * 8 + i) * 8 + t * 2];
        float li = part_ml[(bh * 8 + i) * 8 + t * 2 + 1];
        if (mi > NEGINF) {
            float wgt = __expf(mi - M);
            L += li * wgt;
            acc += part_acc[((size_t)(bh * 8 + i) * 4 + t) * HD_ + d] * wgt;
        }
    }

    float qv = qs[bh * 256 + t * 64 + d];
    float sn[4];
#pragma unroll
    for (int i = 0; i < 4; i++) {
        size_t mi_ = (size_t)b * S_ + CACHE_ + i;
        bool masked = mode ? (mask8[mi_] != 0) : (mask32[mi_] != 0);
        float prod = qv * kn[bh * 256 + i * 64 + d];
        prod += __shfl_xor(prod, 1);
        prod += __shfl_xor(prod, 2);
        prod += __shfl_xor(prod, 4);
        prod += __shfl_xor(prod, 8);
        prod += __shfl_xor(prod, 16);
        prod += __shfl_xor(prod, 32);
        sn[i] = masked ? NEGINF : prod;
    }
    float M2 = M;
#pragma unroll
    for (int i = 0; i < 4; i++) M2 = fmaxf(M2, sn[i]);
    if (M2 > NEGINF) {
        if (M > NEGINF) {
            float wo = __expf(M - M2);
            acc *= wo; L *= wo;
        }
#pragma unroll
        for (int i = 0; i < 4; i++) {
            if (sn[i] > NEGINF) {
                float e = __expf(sn[i] - M2);
                L += e;
                acc += e * vn[bh * 256 + i * 64 + d];
            }
        }
    }
    float o = (L > 0.f) ? acc / L : 0.f;
    attn_out[(size_t)(t * B_ + b) * E_ + h * HD_ + d] = o;
}

// ---------------- output projection, 16x16 tiles, BK=64, float4 LDS reads (512 blocks) ----------------
__global__ __launch_bounds__(256) void oproj_kernel(
    const float* __restrict__ A,
    const float* __restrict__ W, const float* __restrict__ bias,
    float* __restrict__ out)
{
    const int bx = blockIdx.x;            // 512 blocks: 8 rt x 64 ct
    const int rt = bx >> 6, ct = bx & 63;
    const int r0 = rt * 16, c0 = ct * 16;
    const int tid = threadIdx.x;

    __shared__ float A_l[16][68];
    __shared__ float W_l[16][68];
    const int r = tid >> 4, cc = tid & 15;
    float acc = 0.f;

    for (int k0 = 0; k0 < 1024; k0 += 64) {
        __syncthreads();
        if (tid < 128) {
            int j0 = tid * 2;
#pragma unroll
            for (int jj = 0; jj < 2; jj++) {
                int j = j0 + jj;
                int ar = j >> 4, kk = (j & 15) * 4;
                float4 v = *(const float4*)(A + (size_t)(r0 + ar) * 1024 + k0 + kk);
                *(float4*)&A_l[ar][kk] = v;
            }
        } else {
            int j0 = (tid - 128) * 2;
#pragma unroll
            for (int jj = 0; jj < 2; jj++) {
                int j = j0 + jj;
                int wr = j >> 4, kk = (j & 15) * 4;
                float4 v = *(const float4*)(W + (size_t)(c0 + wr) * 1024 + k0 + kk);
                *(float4*)&W_l[wr][kk] = v;
            }
        }
        __syncthreads();
#pragma unroll
        for (int kk = 0; kk < 64; kk += 4) {
            float4 a4 = *(const float4*)&A_l[r][kk];
            float4 w4 = *(const float4*)&W_l[cc][kk];
            acc += a4.x * w4.x + a4.y * w4.y + a4.z * w4.z + a4.w * w4.w;
        }
    }
    const int row = r0 + r, col = c0 + cc;
    out[(size_t)row * 1024 + col] = acc + bias[col];
}

extern "C" void kernel_launch(void* const* d_in, const int* in_sizes, int n_in,
                              void* d_out, int out_size, void* d_ws, size_t ws_size,
                              hipStream_t stream) {
    const float* query = (const float*)d_in[0];
    // d_in[1] = key: unused by the reference (k_new/v_new project from query)
    const unsigned char* mask = (const unsigned char*)d_in[2];
    const float* kcache = (const float*)d_in[3];
    const float* vcache = (const float*)d_in[4];
    const float* Wq = (const float*)d_in[5];
    const float* bq = (const float*)d_in[6];
    const float* Wk = (const float*)d_in[7];
    const float* bk = (const float*)d_in[8];
    const float* Wv = (const float*)d_in[9];
    const float* bv = (const float*)d_in[10];
    const float* Wo = (const float*)d_in[11];
    const float* bo = (const float*)d_in[12];

    char* ws = (char*)d_ws;
    float* qs   = (float*)(ws);                       // 512 KB
    float* kn   = (float*)(ws + ( 512ull << 10));     // 512 KB
    float* vn   = (float*)(ws + (1024ull << 10));     // 512 KB
    float* att  = (float*)(ws + (1536ull << 10));     // 512 KB
    int*   flag = (int*)  (ws + (2048ull << 10));     // 4 B
    int*   cidx = (int*)  (ws + (2049ull << 10));     // 512 KB
    int*   ccnt = (int*)  (ws + (2562ull << 10));     // 128 B
    float* pml  = (float*)(ws + (2563ull << 10));     // 128 KB
    float* pacc = (float*)(ws + (3072ull << 10));     // 4 MB

    prep_kernel<<<32 + 1536, 256, 0, stream>>>(query, Wq, bq, Wk, bk, Wv, bv,
                                               mask, qs, kn, vn, cidx, ccnt, flag);
    attn_kernel<<<512 * SPLIT_, 256, 0, stream>>>(kcache, vcache, qs, cidx, ccnt, pml, pacc);
    merge_kernel<<<512, 256, 0, stream>>>(pml, pacc, qs, kn, vn, mask, flag, att);
    oproj_kernel<<<512, 256, 0, stream>>>(att, Wo, bo, (float*)d_out);
}

// Round 15
// 148.706 us; speedup vs baseline: 1.3166x; 1.0650x over previous
//
#include <hip/hip_runtime.h>

typedef unsigned int u32;
typedef unsigned long long u64;
typedef float f32x4 __attribute__((ext_vector_type(4)));

#define T_ 4
#define B_ 32
#define E_ 1024
#define H_ 16
#define HD_ 64
#define CACHE_ 4096
#define S_ 4100
#define SPLIT_ 2
#define NEGINF (-__builtin_inff())

// ---------------- prep: blocks 0..31 = mask compaction; 32..1567 = QKV proj ----------------
// Proj: 32x32 tiles x split-K4 (512 blocks/matrix), 2x2 reg tile (rows/cols {t,t+16}),
// BK=64, b128 LDS reads (4 B/FMA), float atomicAdd accumulation (ks==0 adds bias).
__global__ __launch_bounds__(256) void prep_kernel(
    const float* __restrict__ query,
    const float* __restrict__ Wq, const float* __restrict__ bq,
    const float* __restrict__ Wk, const float* __restrict__ bk,
    const float* __restrict__ Wv, const float* __restrict__ bv,
    const unsigned char* __restrict__ mask8,
    float* __restrict__ qs, float* __restrict__ kn, float* __restrict__ vn,
    int* __restrict__ cidx, int* __restrict__ ccnt, int* __restrict__ flag)
{
    const int tid = threadIdx.x;
    if (blockIdx.x < 32) {
        // ---------- compaction: 2 barriers total ----------
        const int b = blockIdx.x;
        const int w = tid >> 6, l = tid & 63;
        const int* mask32 = (const int*)mask8;
        __shared__ int cnt_s;
        __shared__ int rcnt[64];      // [round*4 + wave]
        __shared__ int roff[64];
        __shared__ int total_s;

        int cnt = 0;
        for (int i = tid; i < 8192; i += 256) cnt += (mask8[i] != 0) ? 1 : 0;
#pragma unroll
        for (int off = 32; off; off >>= 1) cnt += __shfl_xor(cnt, off);
        if (tid == 0) cnt_s = 0;
        __syncthreads();
        if (l == 0) atomicAdd(&cnt_s, cnt);
        __syncthreads();
        const int mode = (cnt_s > 2048) ? 1 : 0;
        if (b == 0 && tid == 0) *flag = mode;

        u32 okbits = 0;
        const size_t mbase = (size_t)b * S_;
#pragma unroll
        for (int r = 0; r < 16; r++) {
            int s = r * 256 + tid;
            bool ok = mode ? (mask8[mbase + s] == 0) : (mask32[mbase + s] == 0);
            okbits |= (ok ? 1u : 0u) << r;
            u64 bal = __ballot(ok);
            if (l == 0) rcnt[r * 4 + w] = (int)__popcll(bal);
        }
        __syncthreads();
        if (tid < 64) {
            int c = rcnt[tid];
            int incl = c;
#pragma unroll
            for (int d = 1; d < 64; d <<= 1) {
                int v = __shfl_up(incl, d);
                if (l >= d) incl += v;
            }
            roff[tid] = incl - c;
            if (tid == 63) total_s = incl;
        }
        __syncthreads();
#pragma unroll
        for (int r = 0; r < 16; r++) {
            bool ok = (okbits >> r) & 1;
            u64 bal = __ballot(ok);
            int pre = (int)__popcll(bal & ((1ull << l) - 1));
            if (ok) cidx[b * CACHE_ + roff[r * 4 + w] + pre] = r * 256 + tid;
        }
        if (tid == 0) ccnt[b] = total_s;
        return;
    }

    // ---------- QKV projection: 32x32 tiles, split-K4, 2x2 reg tile ----------
    const int bx = blockIdx.x - 32;       // 0..1535
    const int mat = bx >> 9;              // 0..2 (512 blocks each)
    const int rem = bx & 511;
    const int ks = rem & 3;               // K-slice 0..3
    const int tile = rem >> 2;            // 0..127
    const int rt = tile >> 5, ct = tile & 31;
    const int r0 = rt * 32, c0 = ct * 32;
    const int kbase = ks * 256;
    const float* W    = (mat == 0) ? Wq : (mat == 1) ? Wk : Wv;
    const float* bias = (mat == 0) ? bq : (mat == 1) ? bk : bv;

    __shared__ float A_l[32][68];         // stride 68: rows 16B-aligned
    __shared__ float W_l[32][68];
    const int tr = tid >> 4, tc = tid & 15;
    float a00 = 0.f, a01 = 0.f, a10 = 0.f, a11 = 0.f;

    for (int k0 = 0; k0 < 256; k0 += 64) {
        __syncthreads();
#pragma unroll
        for (int jj = 0; jj < 2; jj++) {
            int j = tid * 2 + jj;         // 0..511
            int rr = j >> 4, kk = (j & 15) * 4;
            *(float4*)&A_l[rr][kk] =
                *(const float4*)(query + (size_t)(r0 + rr) * 1024 + kbase + k0 + kk);
            *(float4*)&W_l[rr][kk] =
                *(const float4*)(W + (size_t)(c0 + rr) * 1024 + kbase + k0 + kk);
        }
        __syncthreads();
#pragma unroll
        for (int kk = 0; kk < 64; kk += 4) {
            float4 x0 = *(const float4*)&A_l[tr][kk];
            float4 x1 = *(const float4*)&A_l[tr + 16][kk];
            float4 y0 = *(const float4*)&W_l[tc][kk];
            float4 y1 = *(const float4*)&W_l[tc + 16][kk];
            a00 += x0.x * y0.x + x0.y * y0.y + x0.z * y0.z + x0.w * y0.w;
            a01 += x0.x * y1.x + x0.y * y1.y + x0.z * y1.z + x0.w * y1.w;
            a10 += x1.x * y0.x + x1.y * y0.y + x1.z * y0.z + x1.w * y0.w;
            a11 += x1.x * y1.x + x1.y * y1.y + x1.z * y1.z + x1.w * y1.w;
        }
    }
    float av[2][2] = {{a00, a01}, {a10, a11}};
#pragma unroll
    for (int i = 0; i < 2; i++) {
#pragma unroll
        for (int j = 0; j < 2; j++) {
            int row = r0 + tr + i * 16, col = c0 + tc + j * 16;
            int t = row >> 5, b = row & 31;
            int h = col >> 6, d = col & 63;
            size_t oidx = ((size_t)((b * H_ + h) * T_ + t)) * HD_ + d;
            float val = av[i][j];
            if (mat == 0) {
                val *= 0.125f;
                if (ks == 0) val += bias[col] * 0.125f;
                atomicAdd(&qs[oidx], val);
            } else {
                if (ks == 0) val += bias[col];
                atomicAdd((mat == 1 ? kn : vn) + oidx, val);
            }
        }
    }
}

// ---------------- attention: 128B-transaction, lane-local-softmax flash decode ----------------
// (round-11/14 kernel: measured best — compacted gather, nt loads, reg A/B dbuf)
__global__ __launch_bounds__(256, 4) void attn_kernel(
    const float* __restrict__ kcache, const float* __restrict__ vcache,
    const float* __restrict__ qs,
    const int* __restrict__ cidx, const int* __restrict__ ccnt,
    float* __restrict__ part_ml, float* __restrict__ part_acc)
{
    const int bid = blockIdx.x;
    const int bh = bid >> 1, split = bid & 1;
    const int b = bh >> 4;
    const int tid = threadIdx.x;
    const int w = tid >> 6, l = tid & 63;
    const int sub = l & 7, r8 = l >> 3;

    __shared__ float q_l[256];
    __shared__ int cidx_l[2048];

    const int cnt = ccnt[b];
    const int half = (cnt + 1) >> 1;
    const int lo = split * half;
    const int hi = min(cnt, lo + half);
    const int n = hi - lo;

    q_l[tid] = qs[bh * 256 + tid];
    for (int i = tid; i < n; i += 256) cidx_l[i] = cidx[b * CACHE_ + lo + i];
    __syncthreads();

    float4 qa[4], qb[4];
#pragma unroll
    for (int t = 0; t < 4; t++) {
        qa[t] = *(const float4*)&q_l[t * 64 + sub * 4];
        qb[t] = *(const float4*)&q_l[t * 64 + 32 + sub * 4];
    }

    float4 o0[4], o1[4];
#pragma unroll
    for (int t = 0; t < 4; t++) {
        o0[t] = make_float4(0.f, 0.f, 0.f, 0.f);
        o1[t] = make_float4(0.f, 0.f, 0.f, 0.f);
    }
    float m[4] = {NEGINF, NEGINF, NEGINF, NEGINF};
    float L[4] = {0.f, 0.f, 0.f, 0.f};

    const float* kb = kcache + (size_t)bh * (CACHE_ * HD_) + sub * 4;
    const float* vb = vcache + (size_t)bh * (CACHE_ * HD_) + sub * 4;

    const int nch = (n + 31) >> 5;        // 32 rows per block-chunk (8 per wave)
    const int pbase = w * 8 + r8;

    f32x4 kA0, kA1, vA0, vA1, kB0, kB1, vB0, vB1;

#define ISSUE(K0, K1, V0, V1, CC) {                                       \
        int idx_ = cidx_l[min(pbase + (CC) * 32, n - 1)];                  \
        const f32x4* kp_ = (const f32x4*)(kb + ((size_t)idx_ << 6));       \
        const f32x4* vp_ = (const f32x4*)(vb + ((size_t)idx_ << 6));       \
        K0 = __builtin_nontemporal_load(kp_);                              \
        K1 = __builtin_nontemporal_load(kp_ + 8);                          \
        V0 = __builtin_nontemporal_load(vp_);                              \
        V1 = __builtin_nontemporal_load(vp_ + 8);                          \
    }

#define PROCESS(K0, K1, V0, V1, CC) {                                               \
        const bool valid_ = ((CC) * 32 + pbase) < n;                                \
        _Pragma("unroll")                                                           \
        for (int t = 0; t < 4; t++) {                                               \
            float part = qa[t].x * K0.x + qa[t].y * K0.y + qa[t].z * K0.z           \
                       + qa[t].w * K0.w + qb[t].x * K1.x + qb[t].y * K1.y           \
                       + qb[t].z * K1.z + qb[t].w * K1.w;                           \
            part += __shfl_xor(part, 1);                                            \
            part += __shfl_xor(part, 2);                                            \
            part += __shfl_xor(part, 4);                                            \
            float s = valid_ ? part : NEGINF;                                       \
            if (s > m[t] + 8.f) {       /* defer-max: rare rescale */               \
                float fac = __expf(m[t] - s);                                       \
                L[t] *= fac;                                                        \
                o0[t].x *= fac; o0[t].y *= fac; o0[t].z *= fac; o0[t].w *= fac;     \
                o1[t].x *= fac; o1[t].y *= fac; o1[t].z *= fac; o1[t].w *= fac;     \
                m[t] = s;                                                           \
            }                                                                       \
            float e = (s == NEGINF) ? 0.f : __expf(s - m[t]);                       \
            L[t] += e;                                                              \
            o0[t].x += e * V0.x; o0[t].y += e * V0.y;                               \
            o0[t].z += e * V0.z; o0[t].w += e * V0.w;                               \
            o1[t].x += e * V1.x; o1[t].y += e * V1.y;                               \
            o1[t].z += e * V1.z; o1[t].w += e * V1.w;                               \
        }                                                                           \
    }

    if (nch > 0) ISSUE(kA0, kA1, vA0, vA1, 0);
    if (nch > 1) ISSUE(kB0, kB1, vB0, vB1, 1);

    for (int c = 0; c < nch; c += 2) {
        PROCESS(kA0, kA1, vA0, vA1, c);
        if (c + 2 < nch) ISSUE(kA0, kA1, vA0, vA1, c + 2);
        if (c + 1 < nch) {
            PROCESS(kB0, kB1, vB0, vB1, c + 1);
            if (c + 3 < nch) ISSUE(kB0, kB1, vB0, vB1, c + 3);
        }
    }
#undef ISSUE
#undef PROCESS

    // ---- end merge across the 8 r8-groups (lanes differ in bits 3,4,5) ----
    const int pidx = bid * 4 + w;           // [0, 4096)
#pragma unroll
    for (int t = 0; t < 4; t++) {
        float M = m[t];
        M = fmaxf(M, __shfl_xor(M, 8));
        M = fmaxf(M, __shfl_xor(M, 16));
        M = fmaxf(M, __shfl_xor(M, 32));
        float fac = (m[t] == NEGINF) ? 0.f : __expf(m[t] - M);
        float Lr = L[t] * fac;
        Lr += __shfl_xor(Lr, 8);
        Lr += __shfl_xor(Lr, 16);
        Lr += __shfl_xor(Lr, 32);
        float a0x = o0[t].x * fac, a0y = o0[t].y * fac,
              a0z = o0[t].z * fac, a0w = o0[t].w * fac;
        float a1x = o1[t].x * fac, a1y = o1[t].y * fac,
              a1z = o1[t].z * fac, a1w = o1[t].w * fac;
#pragma unroll
        for (int off = 8; off <= 32; off <<= 1) {
            a0x += __shfl_xor(a0x, off); a0y += __shfl_xor(a0y, off);
            a0z += __shfl_xor(a0z, off); a0w += __shfl_xor(a0w, off);
            a1x += __shfl_xor(a1x, off); a1y += __shfl_xor(a1y, off);
            a1z += __shfl_xor(a1z, off); a1w += __shfl_xor(a1w, off);
        }
        if (r8 == 0) {
            *(float4*)&part_acc[((size_t)pidx * 4 + t) * HD_ + sub * 4] =
                make_float4(a0x, a0y, a0z, a0w);
            *(float4*)&part_acc[((size_t)pidx * 4 + t) * HD_ + 32 + sub * 4] =
                make_float4(a1x, a1y, a1z, a1w);
        }
        if (l == 0) {
            part_ml[pidx * 8 + t * 2 + 0] = M;
            part_ml[pidx * 8 + t * 2 + 1] = Lr;
        }
    }
}

// ---------------- merge partials + new tokens + normalize ----------------
__global__ __launch_bounds__(256) void merge_kernel(
    const float* __restrict__ part_ml, const float* __restrict__ part_acc,
    const float* __restrict__ qs, const float* __restrict__ kn,
    const float* __restrict__ vn,
    const unsigned char* __restrict__ mask8, const int* __restrict__ flag,
    float* __restrict__ attn_out)
{
    const int bh = blockIdx.x;
    const int b = bh >> 4, h = bh & 15;
    const int tid = threadIdx.x;
    const int t = tid >> 6, d = tid & 63;
    const int mode = *flag;
    const int* mask32 = (const int*)mask8;

    float M = NEGINF;
#pragma unroll
    for (int i = 0; i < 8; i++) M = fmaxf(M, part_ml[(bh * 8 + i) * 8 + t * 2]);
    float acc = 0.f, L = 0.f;
#pragma unroll
    for (int i = 0; i < 8; i++) {
        float mi = part_ml[(bh * 8 + i) * 8 + t * 2];
        float li = part_ml[(bh * 8 + i) * 8 + t * 2 + 1];
        if (mi > NEGINF) {
            float wgt = __expf(mi - M);
            L += li * wgt;
            acc += part_acc[((size_t)(bh * 8 + i) * 4 + t) * HD_ + d] * wgt;
        }
    }

    float qv = qs[bh * 256 + t * 64 + d];
    float sn[4];
#pragma unroll
    for (int i = 0; i < 4; i++) {
        size_t mi_ = (size_t)b * S_ + CACHE_ + i;
        bool masked = mode ? (mask8[mi_] != 0) : (mask32[mi_] != 0);
        float prod = qv * kn[bh * 256 + i * 64 + d];
        prod += __shfl_xor(prod, 1);
        prod += __shfl_xor(prod, 2);
        prod += __shfl_xor(prod, 4);
        prod += __shfl_xor(prod, 8);
        prod += __shfl_xor(prod, 16);
        prod += __shfl_xor(prod, 32);
        sn[i] = masked ? NEGINF : prod;
    }
    float M2 = M;
#pragma unroll
    for (int i = 0; i < 4; i++) M2 = fmaxf(M2, sn[i]);
    if (M2 > NEGINF) {
        if (M > NEGINF) {
            float wo = __expf(M - M2);
            acc *= wo; L *= wo;
        }
#pragma unroll
        for (int i = 0; i < 4; i++) {
            if (sn[i] > NEGINF) {
                float e = __expf(sn[i] - M2);
                L += e;
                acc += e * vn[bh * 256 + i * 64 + d];
            }
        }
    }
    float o = (L > 0.f) ? acc / L : 0.f;
    attn_out[(size_t)(t * B_ + b) * E_ + h * HD_ + d] = o;
}

// ---------------- output projection: 32x32 tiles, split-K4, 2x2 reg tile (512 blocks) ----------------
__global__ __launch_bounds__(256) void oproj_kernel(
    const float* __restrict__ A,
    const float* __restrict__ W, const float* __restrict__ bias,
    float* __restrict__ out)
{
    const int bx = blockIdx.x;            // 512 = 128 tiles x 4 K-slices
    const int ks = bx & 3;
    const int tile = bx >> 2;             // 0..127
    const int rt = tile >> 5, ct = tile & 31;
    const int r0 = rt * 32, c0 = ct * 32;
    const int kbase = ks * 256;
    const int tid = threadIdx.x;

    __shared__ float A_l[32][68];
    __shared__ float W_l[32][68];
    const int tr = tid >> 4, tc = tid & 15;
    float a00 = 0.f, a01 = 0.f, a10 = 0.f, a11 = 0.f;

    for (int k0 = 0; k0 < 256; k0 += 64) {
        __syncthreads();
#pragma unroll
        for (int jj = 0; jj < 2; jj++) {
            int j = tid * 2 + jj;
            int rr = j >> 4, kk = (j & 15) * 4;
            *(float4*)&A_l[rr][kk] =
                *(const float4*)(A + (size_t)(r0 + rr) * 1024 + kbase + k0 + kk);
            *(float4*)&W_l[rr][kk] =
                *(const float4*)(W + (size_t)(c0 + rr) * 1024 + kbase + k0 + kk);
        }
        __syncthreads();
#pragma unroll
        for (int kk = 0; kk < 64; kk += 4) {
            float4 x0 = *(const float4*)&A_l[tr][kk];
            float4 x1 = *(const float4*)&A_l[tr + 16][kk];
            float4 y0 = *(const float4*)&W_l[tc][kk];
            float4 y1 = *(const float4*)&W_l[tc + 16][kk];
            a00 += x0.x * y0.x + x0.y * y0.y + x0.z * y0.z + x0.w * y0.w;
            a01 += x0.x * y1.x + x0.y * y1.y + x0.z * y1.z + x0.w * y1.w;
            a10 += x1.x * y0.x + x1.y * y0.y + x1.z * y0.z + x1.w * y0.w;
            a11 += x1.x * y1.x + x1.y * y1.y + x1.z * y1.z + x1.w * y1.w;
        }
    }
    float av[2][2] = {{a00, a01}, {a10, a11}};
#pragma unroll
    for (int i = 0; i < 2; i++) {
#pragma unroll
        for (int j = 0; j < 2; j++) {
            int row = r0 + tr + i * 16, col = c0 + tc + j * 16;
            float val = av[i][j];
            if (ks == 0) val += bias[col];
            atomicAdd(&out[(size_t)row * 1024 + col], val);
        }
    }
}

extern "C" void kernel_launch(void* const* d_in, const int* in_sizes, int n_in,
                              void* d_out, int out_size, void* d_ws, size_t ws_size,
                              hipStream_t stream) {
    const float* query = (const float*)d_in[0];
    // d_in[1] = key: unused by the reference (k_new/v_new project from query)
    const unsigned char* mask = (const unsigned char*)d_in[2];
    const float* kcache = (const float*)d_in[3];
    const float* vcache = (const float*)d_in[4];
    const float* Wq = (const float*)d_in[5];
    const float* bq = (const float*)d_in[6];
    const float* Wk = (const float*)d_in[7];
    const float* bk = (const float*)d_in[8];
    const float* Wv = (const float*)d_in[9];
    const float* bv = (const float*)d_in[10];
    const float* Wo = (const float*)d_in[11];
    const float* bo = (const float*)d_in[12];

    char* ws = (char*)d_ws;
    float* qs   = (float*)(ws);                       // 512 KB
    float* kn   = (float*)(ws + ( 512ull << 10));     // 512 KB
    float* vn   = (float*)(ws + (1024ull << 10));     // 512 KB
    float* att  = (float*)(ws + (1536ull << 10));     // 512 KB
    int*   flag = (int*)  (ws + (2048ull << 10));     // 4 B
    int*   cidx = (int*)  (ws + (2049ull << 10));     // 512 KB
    int*   ccnt = (int*)  (ws + (2562ull << 10));     // 128 B
    float* pml  = (float*)(ws + (2563ull << 10));     // 128 KB
    float* pacc = (float*)(ws + (3072ull << 10));     // 4 MB

    // zero split-K accumulation targets (graph-capture-safe async ops)
    hipMemsetAsync(ws, 0, 1536ull << 10, stream);               // qs, kn, vn
    hipMemsetAsync(d_out, 0, (size_t)out_size * 4, stream);     // oproj target

    prep_kernel<<<32 + 1536, 256, 0, stream>>>(query, Wq, bq, Wk, bk, Wv, bv,
                                               mask, qs, kn, vn, cidx, ccnt, flag);
    attn_kernel<<<512 * SPLIT_, 256, 0, stream>>>(kcache, vcache, qs, cidx, ccnt, pml, pacc);
    merge_kernel<<<512, 256, 0, stream>>>(pml, pacc, qs, kn, vn, mask, flag, att);
    oproj_kernel<<<512, 256, 0, stream>>>(att, Wo, bo, (float*)d_out);
}